// Round 1
// baseline (191.382 us; speedup 1.0000x reference)
//
#include <hip/hip_runtime.h>
#include <hip/hip_bf16.h>

typedef __attribute__((ext_vector_type(8))) short short8;
typedef __attribute__((ext_vector_type(4))) float floatx4;

#define BDIM 512

constexpr int kCIN = 256, kCOUT = 256, kH = 64, kW = 64;
constexpr int BK = 32;                 // ci per chunk
constexpr int NCHUNK = kCIN / BK;      // 8
constexpr int XR = 4, XC = 66, NPIX = XR * XC;  // 264 halo pixels
constexpr int HW = kH * kW;

// 16B-granule XOR swizzle within (pairs of) 64B rows: 2-way conflicts only
__device__ __forceinline__ int swz16(int row, int g) {
    return ((g ^ ((row >> 1) & 3)) << 4);
}

__device__ __forceinline__ unsigned short f2bf(float f) {
    unsigned u = __float_as_uint(f);
    u += 0x7fffu + ((u >> 16) & 1u);   // RNE
    return (unsigned short)(u >> 16);
}

// weight[co][ci][kh][kw] fp32  ->  Wt[kk][co][ci] bf16  (kk = kh*3+kw)
__global__ void wt_transform_kernel(const float* __restrict__ wsrc,
                                    unsigned short* __restrict__ wt) {
    int idx = blockIdx.x * 256 + threadIdx.x;
    if (idx >= 9 * 256 * 256) return;
    int ci = idx & 255;
    int co = (idx >> 8) & 255;
    int kk = idx >> 16;
    wt[idx] = f2bf(wsrc[(co * 256 + ci) * 9 + kk]);
}

// out[b][co][h][w] = sum_{ci,kh,kw} x[b][ci][h+kh-1][w+kw-1]*W[co][ci][kh][kw] + bias[co]
// Block: 256 cout x 128 pixels (2 rows of one image). 8 waves = 4(co) x 2(row).
__global__ __launch_bounds__(BDIM)
void conv3x3_mfma_kernel(const float* __restrict__ x,
                         const unsigned short* __restrict__ wt,
                         const float* __restrict__ bias,
                         float* __restrict__ out) {
    __shared__ __align__(16) char xs[NPIX * 64];    // [pix=r*66+c][32 ci] bf16, swizzled
    __shared__ __align__(16) char ws[2][256 * 64];  // [co][32 ci] bf16, swizzled, dbuf

    const int bid = blockIdx.x;
    const int b = bid >> 5;            // 32 h-tiles per image
    const int h0 = (bid & 31) * 2;

    const int tid = threadIdx.x;
    const int wv = tid >> 6;
    const int l = tid & 63;
    const int lo = l & 15;
    const int hi = l >> 4;
    const int co0w = (wv & 3) * 64;    // wave's cout base
    const int wpix = wv >> 2;          // wave's output row (0/1)

    const float* xb = x + (size_t)b * kCIN * HW;

    floatx4 acc[4][4] = {};            // [co frag][pix frag]

    for (int chunk = 0; chunk < NCHUNK; ++chunk) {
        const int ci0 = chunk * BK;

        // ---- stage x halo tile: rows h0-1..h0+2, cols -1..64, ci0..ci0+31 ----
        // task = ((g*XR + r)*XC + c); consecutive threads -> consecutive c (coalesced)
        for (int t = tid; t < NPIX * 4; t += BDIM) {
            int g = t / NPIX;
            int rem = t - g * NPIX;
            int r = rem / XC;
            int c = rem - r * XC;
            int ih = h0 - 1 + r;
            int iw = c - 1;
            float v[8];
            if ((unsigned)ih < (unsigned)kH && (unsigned)iw < (unsigned)kW) {
                const float* p = xb + (size_t)(ci0 + g * 8) * HW + ih * kW + iw;
                #pragma unroll
                for (int j = 0; j < 8; ++j) v[j] = p[(size_t)j * HW];
            } else {
                #pragma unroll
                for (int j = 0; j < 8; ++j) v[j] = 0.f;
            }
            union { short8 s8; unsigned short u[8]; } pk;
            #pragma unroll
            for (int j = 0; j < 8; ++j) pk.u[j] = f2bf(v[j]);
            int pix = r * XC + c;
            *(short8*)(xs + pix * 64 + swz16(pix, g)) = pk.s8;
        }
        // ---- stage W tile for kk=0 into buf 0 ----
        {
            const unsigned short* wsrcp = wt + ci0;   // kk = 0
            for (int t = tid; t < 1024; t += BDIM) {
                int co = t >> 2, g = t & 3;
                short8 v = *(const short8*)(wsrcp + co * 256 + g * 8);
                *(short8*)(ws[0] + co * 64 + swz16(co, g)) = v;
            }
        }
        __syncthreads();

        for (int kk = 0; kk < 9; ++kk) {
            // prefetch next W tile into the other buffer
            if (kk < 8) {
                const unsigned short* wsrcp = wt + (size_t)(kk + 1) * 65536 + ci0;
                char* wbuf = ws[(kk + 1) & 1];
                for (int t = tid; t < 1024; t += BDIM) {
                    int co = t >> 2, g = t & 3;
                    short8 v = *(const short8*)(wsrcp + co * 256 + g * 8);
                    *(short8*)(wbuf + co * 64 + swz16(co, g)) = v;
                }
            }
            // ---- MFMA: A = W[co][ci], B = x[ci][pix] ----
            {
                const char* wbuf = ws[kk & 1];
                short8 a[4], bfr[4];
                #pragma unroll
                for (int i = 0; i < 4; ++i) {
                    int co = co0w + i * 16 + lo;
                    a[i] = *(const short8*)(wbuf + co * 64 + swz16(co, hi));
                }
                const int kh = kk / 3, kw = kk - kh * 3;
                const int r = wpix + kh;
                #pragma unroll
                for (int f = 0; f < 4; ++f) {
                    int pix = r * XC + f * 16 + lo + kw;
                    bfr[f] = *(const short8*)(xs + pix * 64 + swz16(pix, hi));
                }
                #pragma unroll
                for (int i = 0; i < 4; ++i) {
                    #pragma unroll
                    for (int f = 0; f < 4; ++f) {
                        acc[i][f] = __builtin_amdgcn_mfma_f32_16x16x32_bf16(
                            a[i], bfr[f], acc[i][f], 0, 0, 0);
                    }
                }
            }
            __syncthreads();
        }
    }

    // ---- epilogue: C/D layout col=lane&15 (pixel w), row=(lane>>4)*4+reg (co) ----
    const int h = h0 + wpix;
    float* op = out + (size_t)b * kCOUT * HW;
    #pragma unroll
    for (int i = 0; i < 4; ++i) {
        #pragma unroll
        for (int rg = 0; rg < 4; ++rg) {
            int co = co0w + i * 16 + hi * 4 + rg;
            float bv = bias[co];
            #pragma unroll
            for (int f = 0; f < 4; ++f) {
                int wcol = f * 16 + lo;
                op[((size_t)co * kH + h) * kW + wcol] = acc[i][f][rg] + bv;
            }
        }
    }
}

extern "C" void kernel_launch(void* const* d_in, const int* in_sizes, int n_in,
                              void* d_out, int out_size, void* d_ws, size_t ws_size,
                              hipStream_t stream) {
    const float* x    = (const float*)d_in[0];
    const float* wsrc = (const float*)d_in[1];
    const float* bias = (const float*)d_in[2];
    float* out = (float*)d_out;
    unsigned short* wt = (unsigned short*)d_ws;  // 9*256*256*2 = 1.18 MB scratch

    hipLaunchKernelGGL(wt_transform_kernel, dim3((9 * 256 * 256 + 255) / 256),
                       dim3(256), 0, stream, wsrc, wt);

    const int kB = 32;
    hipLaunchKernelGGL(conv3x3_mfma_kernel, dim3(kB * (kH / 2)), dim3(BDIM),
                       0, stream, x, wt, bias, out);
}